// Round 1
// baseline (2881.372 us; speedup 1.0000x reference)
//
#include <hip/hip_runtime.h>

// FPS (farthest point sampling) + gather for B=16, N=65536, S=512, C=64.
// Decomposition: 16 WGs per batch, each owns a 4096-pt chunk in LDS.
// Cross-WG argmax per iteration via device-scope atomic slots in d_ws
// (double-buffered by iteration parity, iteration-tagged, 1 round trip).

#define NB   16
#define NPTS 65536
#define NS   512
#define WPB  16                 // workgroups per batch (power of 2)
#define CHUNK (NPTS / WPB)      // 4096 points per WG
#define NTHR 256
#define PPT  (CHUNK / NTHR)     // 16 points per thread
#define NWAVE (NTHR / 64)       // 4 waves per WG
#define SPW  (NS / WPB)         // 32 samples gathered per WG

// Exact fp32, reference op order, no FMA contraction:
__device__ __forceinline__ float sqdist3(float x, float y, float z,
                                         float cx, float cy, float cz) {
    float dx = __fsub_rn(x, cx);
    float dy = __fsub_rn(y, cy);
    float dz = __fsub_rn(z, cz);
    return __fadd_rn(__fadd_rn(__fmul_rn(dx, dx), __fmul_rn(dy, dy)),
                     __fmul_rn(dz, dz));
}

__global__ void __launch_bounds__(NTHR, 1)
fps_kernel(const float* __restrict__ xyz, const float* __restrict__ feat,
           float* __restrict__ out, unsigned long long* __restrict__ slots) {
    const int wg   = blockIdx.x & (WPB - 1);
    const int b    = blockIdx.x / WPB;
    const int tid  = threadIdx.x;
    const int lane = tid & 63;
    const int wave = tid >> 6;

    __shared__ float lx[CHUNK], ly[CHUNK], lz[CHUNK];  // SoA xyz chunk (48 KB)
    __shared__ int   sel[NS];                          // selected indices
    __shared__ float cent[3];                          // current centroid
    __shared__ float wbd[NWAVE];
    __shared__ int   wbi[NWAVE];

    const float* bx  = xyz + (size_t)b * NPTS * 3;
    const int   base = wg * CHUNK;

    // One-time chunk load global -> LDS (SoA de-interleave).
    for (int k = 0; k < PPT; ++k) {
        int p = tid + k * NTHR;
        int g = base + p;
        lx[p] = bx[3 * g + 0];
        ly[p] = bx[3 * g + 1];
        lz[p] = bx[3 * g + 2];
    }
    float dmin[PPT];
#pragma unroll
    for (int k = 0; k < PPT; ++k) dmin[k] = 1e10f;   // reference BIG

    if (tid == 0) {
        sel[0] = 0;                                   // seed point 0
        cent[0] = bx[0]; cent[1] = bx[1]; cent[2] = bx[2];
    }
    __syncthreads();

    for (int it = 1; it < NS; ++it) {
        const float cx = cent[0], cy = cent[1], cz = cent[2];
        float bd = -1.0f; int bi = 0;
#pragma unroll
        for (int k = 0; k < PPT; ++k) {
            int p = tid + k * NTHR;                   // ascending global idx per thread
            float d  = sqdist3(lx[p], ly[p], lz[p], cx, cy, cz);
            float dm = fminf(dmin[k], d);
            dmin[k] = dm;
            if (dm > bd) { bd = dm; bi = base + p; }  // strict > keeps min idx
        }
        // wave reduction: max dist, tie -> min global index
        for (int off = 32; off >= 1; off >>= 1) {
            float od = __shfl_down(bd, off, 64);
            int   oi = __shfl_down(bi, off, 64);
            if (od > bd || (od == bd && oi < bi)) { bd = od; bi = oi; }
        }
        if (lane == 0) { wbd[wave] = bd; wbi[wave] = bi; }
        __syncthreads();
        if (tid == 0) {
            for (int w = 1; w < NWAVE; ++w) {
                float od = wbd[w]; int oi = wbi[w];
                if (od > bd || (od == bd && oi < bi)) { bd = od; bi = oi; }
            }
            // pack: [63:32]=dist bits, [31:16]=iteration tag, [15:0]=idx
            unsigned long long v =
                ((unsigned long long)__float_as_uint(bd) << 32) |
                ((unsigned long long)(unsigned)it << 16) |
                (unsigned long long)(unsigned)bi;
            __hip_atomic_store(
                &slots[((size_t)(it & 1) * NB + b) * WPB + wg], v,
                __ATOMIC_RELEASE, __HIP_MEMORY_SCOPE_AGENT);
        }
        // all-to-all: 16 lanes of wave 0 spin on the batch's 16 slots
        if (wave == 0 && lane < WPB) {
            unsigned long long* sp =
                &slots[((size_t)(it & 1) * NB + b) * WPB + lane];
            unsigned long long v;
            for (;;) {
                v = __hip_atomic_load(sp, __ATOMIC_ACQUIRE,
                                      __HIP_MEMORY_SCOPE_AGENT);
                if (((unsigned)(v >> 16) & 0xFFFFu) == (unsigned)it) break;
                __builtin_amdgcn_s_sleep(1);
            }
            float d2 = __uint_as_float((unsigned)(v >> 32));
            int   i2 = (int)(v & 0xFFFFu);
            for (int off = 8; off >= 1; off >>= 1) {
                float od = __shfl_down(d2, off, 64);
                int   oi = __shfl_down(i2, off, 64);
                if (lane + off < WPB) {
                    if (od > d2 || (od == d2 && oi < i2)) { d2 = od; i2 = oi; }
                }
            }
            if (lane == 0) {
                sel[it] = i2;
                cent[0] = bx[3 * i2 + 0];
                cent[1] = bx[3 * i2 + 1];
                cent[2] = bx[3 * i2 + 2];
            }
        }
        __syncthreads();
    }

    // Gather: this WG writes samples [wg*32, wg*32+32).
    const float* bf   = feat + (size_t)b * NPTS * 64;
    float*       oxyz = out + (size_t)b * NS * 3;
    float*       of   = out + (size_t)NB * NS * 3 + (size_t)b * NS * 64;
    const int c  = tid & 63;
    const int sr = tid >> 6;                          // 0..3
    for (int k = 0; k < SPW / NWAVE; ++k) {
        int s = wg * SPW + k * NWAVE + sr;
        int p = sel[s];
        of[(size_t)s * 64 + c] = bf[(size_t)p * 64 + c];
    }
    if (tid < SPW * 3) {
        int s    = wg * SPW + tid / 3;
        int comp = tid % 3;
        oxyz[s * 3 + comp] = bx[sel[s] * 3 + comp];
    }
}

extern "C" void kernel_launch(void* const* d_in, const int* in_sizes, int n_in,
                              void* d_out, int out_size, void* d_ws, size_t ws_size,
                              hipStream_t stream) {
    const float* xyz = (const float*)d_in[0];
    const float* f   = (const float*)d_in[1];
    float* out = (float*)d_out;
    unsigned long long* slots = (unsigned long long*)d_ws;
    // Clear iteration tags (ws is poisoned 0xAA; tag 0 is never a valid iter).
    hipMemsetAsync(d_ws, 0, (size_t)2 * NB * WPB * sizeof(unsigned long long),
                   stream);
    fps_kernel<<<dim3(NB * WPB), dim3(NTHR), 0, stream>>>(xyz, f, out, slots);
}

// Round 2
// 1530.967 us; speedup vs baseline: 1.8821x; 1.8821x over previous
//
#include <hip/hip_runtime.h>

// FPS (farthest point sampling) + gather for B=16, N=65536, S=512, C=64.
// Decomposition: 16 WGs per batch, each owns a 4096-pt chunk in REGISTERS
// (16 pts/thread x 3 floats). Cross-WG argmax per iteration via RELAXED
// device-scope atomic slots in d_ws (double-buffered by parity, iteration-
// tagged). Payload is fully packed in the 64-bit word -> no acq/rel fences
// needed (gfx950 agent acquire/release emit buffer_inv / buffer_wbl2, which
// was the 5us/iter cost in round 1).

#define NB   16
#define NPTS 65536
#define NS   512
#define WPB  16                 // workgroups per batch
#define CHUNK (NPTS / WPB)      // 4096 points per WG
#define NTHR 256
#define PPT  (CHUNK / NTHR)     // 16 points per thread
#define NWAVE (NTHR / 64)       // 4 waves per WG
#define SPW  (NS / WPB)         // 32 samples gathered per WG

// Exact fp32, reference op order, no FMA contraction:
__device__ __forceinline__ float sqdist3(float x, float y, float z,
                                         float cx, float cy, float cz) {
    float dx = __fsub_rn(x, cx);
    float dy = __fsub_rn(y, cy);
    float dz = __fsub_rn(z, cz);
    return __fadd_rn(__fadd_rn(__fmul_rn(dx, dx), __fmul_rn(dy, dy)),
                     __fmul_rn(dz, dz));
}

__global__ void __launch_bounds__(NTHR, 1)
fps_kernel(const float* __restrict__ xyz, const float* __restrict__ feat,
           float* __restrict__ out, unsigned long long* __restrict__ slots) {
    const int wg   = blockIdx.x & (WPB - 1);
    const int b    = blockIdx.x / WPB;
    const int tid  = threadIdx.x;
    const int lane = tid & 63;
    const int wave = tid >> 6;

    __shared__ int   sel[NS];      // selected indices (for the final gather)
    __shared__ float cent[3];      // current centroid
    __shared__ float wbd[NWAVE];
    __shared__ int   wbi[NWAVE];

    const float* bx  = xyz + (size_t)b * NPTS * 3;
    const int   base = wg * CHUNK;

    // One-time chunk load global -> registers (SoA in regs, 48 VGPRs).
    float rx[PPT], ry[PPT], rz[PPT], dmin[PPT];
#pragma unroll
    for (int k = 0; k < PPT; ++k) {
        int g = base + tid + k * NTHR;
        rx[k] = bx[3 * g + 0];
        ry[k] = bx[3 * g + 1];
        rz[k] = bx[3 * g + 2];
        dmin[k] = 1e10f;                              // reference BIG
    }

    if (tid == 0) {
        sel[0] = 0;                                   // seed point 0
        cent[0] = bx[0]; cent[1] = bx[1]; cent[2] = bx[2];
    }
    __syncthreads();

    for (int it = 1; it < NS; ++it) {
        const float cx = cent[0], cy = cent[1], cz = cent[2];
        float bd = -1.0f; int bi = 0;
#pragma unroll
        for (int k = 0; k < PPT; ++k) {
            float d  = sqdist3(rx[k], ry[k], rz[k], cx, cy, cz);
            float dm = fminf(dmin[k], d);
            dmin[k] = dm;
            if (dm > bd) { bd = dm; bi = base + tid + k * NTHR; } // strict > keeps min idx
        }
        // wave reduction: max dist, tie -> min global index
        for (int off = 32; off >= 1; off >>= 1) {
            float od = __shfl_down(bd, off, 64);
            int   oi = __shfl_down(bi, off, 64);
            if (od > bd || (od == bd && oi < bi)) { bd = od; bi = oi; }
        }
        if (lane == 0) { wbd[wave] = bd; wbi[wave] = bi; }
        __syncthreads();
        if (tid == 0) {
            for (int w = 1; w < NWAVE; ++w) {
                float od = wbd[w]; int oi = wbi[w];
                if (od > bd || (od == bd && oi < bi)) { bd = od; bi = oi; }
            }
            // pack: [63:32]=dist bits, [31:16]=iteration tag, [15:0]=idx
            unsigned long long v =
                ((unsigned long long)__float_as_uint(bd) << 32) |
                ((unsigned long long)(unsigned)it << 16) |
                (unsigned long long)(unsigned)bi;
            __hip_atomic_store(
                &slots[((size_t)(it & 1) * NB + b) * WPB + wg], v,
                __ATOMIC_RELAXED, __HIP_MEMORY_SCOPE_AGENT);
        }
        // all-to-all: 16 lanes of wave 0 spin on the batch's 16 slots
        if (wave == 0 && lane < WPB) {
            unsigned long long* sp =
                &slots[((size_t)(it & 1) * NB + b) * WPB + lane];
            unsigned long long v;
            for (;;) {
                v = __hip_atomic_load(sp, __ATOMIC_RELAXED,
                                      __HIP_MEMORY_SCOPE_AGENT);
                if (((unsigned)(v >> 16) & 0xFFFFu) == (unsigned)it) break;
                __builtin_amdgcn_s_sleep(1);
            }
            float d2 = __uint_as_float((unsigned)(v >> 32));
            int   i2 = (int)(v & 0xFFFFu);
            // prefetch THIS candidate's coords (overlaps with the reduce)
            float px = bx[3 * i2 + 0];
            float py = bx[3 * i2 + 1];
            float pz = bx[3 * i2 + 2];
            int   wl = lane;                          // winning lane tracker
            for (int off = 8; off >= 1; off >>= 1) {
                float od = __shfl_down(d2, off, 64);
                int   oi = __shfl_down(i2, off, 64);
                int   ol = __shfl_down(wl, off, 64);
                if (lane + off < WPB) {
                    if (od > d2 || (od == d2 && oi < i2)) {
                        d2 = od; i2 = oi; wl = ol;
                    }
                }
            }
            int w = __shfl(wl, 0, 64);                // winner lane, broadcast
            float wxc = __shfl(px, w, 64);
            float wyc = __shfl(py, w, 64);
            float wzc = __shfl(pz, w, 64);
            if (lane == 0) {
                sel[it] = i2;
                cent[0] = wxc; cent[1] = wyc; cent[2] = wzc;
            }
        }
        __syncthreads();
    }

    // Gather: this WG writes samples [wg*32, wg*32+32).
    const float* bf   = feat + (size_t)b * NPTS * 64;
    float*       oxyz = out + (size_t)b * NS * 3;
    float*       of   = out + (size_t)NB * NS * 3 + (size_t)b * NS * 64;
    const int c  = tid & 63;
    const int sr = tid >> 6;                          // 0..3
    for (int k = 0; k < SPW / NWAVE; ++k) {
        int s = wg * SPW + k * NWAVE + sr;
        int p = sel[s];
        of[(size_t)s * 64 + c] = bf[(size_t)p * 64 + c];
    }
    if (tid < SPW * 3) {
        int s    = wg * SPW + tid / 3;
        int comp = tid % 3;
        oxyz[s * 3 + comp] = bx[sel[s] * 3 + comp];
    }
}

extern "C" void kernel_launch(void* const* d_in, const int* in_sizes, int n_in,
                              void* d_out, int out_size, void* d_ws, size_t ws_size,
                              hipStream_t stream) {
    const float* xyz = (const float*)d_in[0];
    const float* f   = (const float*)d_in[1];
    float* out = (float*)d_out;
    unsigned long long* slots = (unsigned long long*)d_ws;
    // Clear iteration tags (ws is poisoned 0xAA; tag 0xAAAA never matches).
    hipMemsetAsync(d_ws, 0, (size_t)2 * NB * WPB * sizeof(unsigned long long),
                   stream);
    fps_kernel<<<dim3(NB * WPB), dim3(NTHR), 0, stream>>>(xyz, f, out, slots);
}